// Round 5
// baseline (139.678 us; speedup 1.0000x reference)
//
#include <hip/hip_runtime.h>

#define GRID   64
#define CELLS  (GRID * GRID)
#define BATCH  4
#define NV     512
#define NNET   2000
#define MAXPIN 8
#define NB     32            // nets per stage-A block
#define NPART  63            // ceil(2000/32)
#define NSLICE 8             // stage-B row-slice blocks per batch
#define SROWS  14            // 8 output rows + 3 halo each side

struct SyncBlock {
    int   cnt1[BATCH];            // stage-A completion count
    int   cnt2[BATCH];            // stage-B completion count
    float pen[BATCH][NSLICE];     // penalty shares
};

// sigma(a)*sigma(b) = 1 / ((1+e^-a)(1+e^-b)) : 2 exp, 1 divide
__device__ __forceinline__ float sig2(float a, float b) {
    float e1 = __expf(-a);
    float e2 = __expf(-b);
    return 1.0f / ((1.0f + e1) * (1.0f + e2));
}

// Fused: blocks pb<NPART do stage A (32 nets -> private 64x64 partial);
// blocks pb>=NPART spin on a device-scope counter, then do stage B
// (slice reduce across 63 partials + separable 7-tap Gaussian + penalty).
// All 284 blocks are co-resident (512 thr, 16.5KB LDS -> 4 blocks/CU), so
// the spin cannot deadlock regardless of dispatch order.
__global__ __launch_bounds__(512)
void rudy_fused_kernel(const float* __restrict__ positions,
                       const float* __restrict__ pin_offsets,
                       const int*   __restrict__ net_to_pin,
                       const int*   __restrict__ pin_to_macro,
                       float* __restrict__ partial,
                       SyncBlock*   __restrict__ sync,
                       float* __restrict__ out_penalty,
                       float* __restrict__ out_smooth) {
    const int pb = blockIdx.x;
    const int b  = blockIdx.y;
    const int t  = threadIdx.x;

    __shared__ union {
        struct {
            float inx[NB][GRID];      // in_x * inv_size (folded)
            float iny[NB][GRID];
            float xmin[NB], xmax[NB], ymin[NB], ymax[NB], inv[NB];
        } a;
        struct {
            float tile[SROWS][GRID];
            float tmp [SROWS][GRID];
            float red [8];
        } s;
    } sm;

    if (pb < NPART) {
        // ================= Stage A =================
        const int n0 = pb * NB;

        // ---- A1: bbox per net, 8 lanes per net, threads 0..255 ----
        if (t < 256) {
            const int nl = t >> 3;
            const int j  = t & 7;
            const int n  = n0 + nl;
            int pi = (n < NNET) ? net_to_pin[n * MAXPIN + j] : -1;
            int sp = pi > 0 ? pi : 0;
            int v  = pin_to_macro[sp];
            float px = positions[(b * NV + v) * 2 + 0] + pin_offsets[sp * 2 + 0];
            float py = positions[(b * NV + v) * 2 + 1] + pin_offsets[sp * 2 + 1];
            bool valid = pi >= 0;
            float xmx = valid ? px : -1e9f;
            float xmn = valid ? px :  1e9f;
            float ymx = valid ? py : -1e9f;
            float ymn = valid ? py :  1e9f;
            #pragma unroll
            for (int off = 1; off < 8; off <<= 1) {
                xmx = fmaxf(xmx, __shfl_xor(xmx, off, 64));
                xmn = fminf(xmn, __shfl_xor(xmn, off, 64));
                ymx = fmaxf(ymx, __shfl_xor(ymx, off, 64));
                ymn = fminf(ymn, __shfl_xor(ymn, off, 64));
            }
            if (j == 0) {
                float xming = (xmn + 1.0f) * 31.5f;
                float xmaxg = (xmx + 1.0f) * 31.5f;
                float yming = (ymn + 1.0f) * 31.5f;
                float ymaxg = (ymx + 1.0f) * 31.5f;
                float size = fmaxf((xmaxg - xming + 1.0f) * (ymaxg - yming + 1.0f), 1.0f);
                sm.a.xmin[nl] = xming; sm.a.xmax[nl] = xmaxg;
                sm.a.ymin[nl] = yming; sm.a.ymax[nl] = ymaxg;
                sm.a.inv[nl]  = 1.0f / size;
            }
        }
        __syncthreads();

        // ---- A2: 4096 indicator values, 8 per thread ----
        #pragma unroll
        for (int i = 0; i < 8; ++i) {
            int vv    = i * 512 + t;
            int n     = vv >> 7;
            int rem   = vv & 127;
            int which = rem >> 6;         // 0 = x, 1 = y
            int coord = rem & 63;
            float c  = (float)coord;
            float lo = which ? sm.a.ymin[n] : sm.a.xmin[n];
            float hi = which ? sm.a.ymax[n] : sm.a.xmax[n];
            float val = sig2(2.0f * (c - lo + 0.5f), 2.0f * (hi - c + 0.5f));
            if (which) sm.a.iny[n][coord] = val;
            else       sm.a.inx[n][coord] = val * sm.a.inv[n];
        }
        __syncthreads();

        // ---- C: rank-1 accumulate, 8 cells/thread over 32 nets ----
        const int lane = t & 63;        // x coordinate
        const int w    = t >> 6;        // rows y = w*8 .. w*8+7
        float acc[8];
        #pragma unroll
        for (int k = 0; k < 8; ++k) acc[k] = 0.0f;

        for (int n = 0; n < NB; ++n) {
            float xv = sm.a.inx[n][lane];
            const float4* iny4 = (const float4*)&sm.a.iny[n][w * 8];
            #pragma unroll
            for (int k4 = 0; k4 < 2; ++k4) {
                float4 yv = iny4[k4];
                acc[k4 * 4 + 0] += yv.x * xv;
                acc[k4 * 4 + 1] += yv.y * xv;
                acc[k4 * 4 + 2] += yv.z * xv;
                acc[k4 * 4 + 3] += yv.w * xv;
            }
        }

        float* dst = partial + ((size_t)b * NPART + pb) * CELLS;
        #pragma unroll
        for (int k = 0; k < 8; ++k)
            dst[(w * 8 + k) * GRID + lane] = acc[k];

        // ---- publish: device-scope release ----
        __threadfence();
        __syncthreads();            // all stores (all waves) done before count
        if (t == 0)
            __hip_atomic_fetch_add(&sync->cnt1[b], 1,
                                   __ATOMIC_RELEASE, __HIP_MEMORY_SCOPE_AGENT);
        return;
    }

    // ================= Stage B =================
    const int q  = pb - NPART;      // row slice 0..7
    const int y0 = q * 8;

    if (t == 0) {
        while (__hip_atomic_load(&sync->cnt1[b],
                                 __ATOMIC_ACQUIRE, __HIP_MEMORY_SCOPE_AGENT) < NPART)
            __builtin_amdgcn_s_sleep(2);
    }
    __syncthreads();

    // 1D gaussian, sigma=1.5, ksize=7, normalized
    float g[7];
    {
        float s = 0.0f;
        #pragma unroll
        for (int i = 0; i < 7; ++i) {
            float d = (float)(i - 3);
            g[i] = expf(-d * d / 4.5f);
            s += g[i];
        }
        float inv = 1.0f / s;
        #pragma unroll
        for (int i = 0; i < 7; ++i) g[i] *= inv;
    }

    // ---- reduce slice across 63 partials: 14 rows x 16 float4 ----
    if (t < SROWS * 16) {
        const int r  = t >> 4;
        const int c4 = t & 15;
        const int yy = y0 - 3 + r;
        float4 a0 = {0,0,0,0}, a1 = {0,0,0,0}, a2 = {0,0,0,0}, a3 = {0,0,0,0};
        if (yy >= 0 && yy < GRID) {
            const float4* src = (const float4*)(partial + (size_t)b * NPART * CELLS)
                                + (size_t)yy * 16 + c4;
            int p = 0;
            for (; p + 3 < NPART; p += 4) {
                float4 v0 = src[(size_t)(p + 0) * (CELLS / 4)];
                float4 v1 = src[(size_t)(p + 1) * (CELLS / 4)];
                float4 v2 = src[(size_t)(p + 2) * (CELLS / 4)];
                float4 v3 = src[(size_t)(p + 3) * (CELLS / 4)];
                a0.x += v0.x; a0.y += v0.y; a0.z += v0.z; a0.w += v0.w;
                a1.x += v1.x; a1.y += v1.y; a1.z += v1.z; a1.w += v1.w;
                a2.x += v2.x; a2.y += v2.y; a2.z += v2.z; a2.w += v2.w;
                a3.x += v3.x; a3.y += v3.y; a3.z += v3.z; a3.w += v3.w;
            }
            for (; p < NPART; ++p) {
                float4 v0 = src[(size_t)p * (CELLS / 4)];
                a0.x += v0.x; a0.y += v0.y; a0.z += v0.z; a0.w += v0.w;
            }
            a0.x += a1.x + a2.x + a3.x;
            a0.y += a1.y + a2.y + a3.y;
            a0.z += a1.z + a2.z + a3.z;
            a0.w += a1.w + a2.w + a3.w;
        }
        ((float4*)&sm.s.tile[r][0])[c4] = a0;   // zeros for out-of-range rows
    }
    __syncthreads();

    // ---- horizontal pass (zero x-padding): 896 cells over 512 threads ----
    for (int i = t; i < SROWS * GRID; i += 512) {
        int r = i >> 6, x = i & 63;
        float s = 0.0f;
        #pragma unroll
        for (int d = -3; d <= 3; ++d) {
            int xx = x + d;
            if (xx >= 0 && xx < GRID) s += g[d + 3] * sm.s.tile[r][xx];
        }
        sm.s.tmp[r][x] = s;
    }
    __syncthreads();

    // ---- vertical pass: 512 cells, exactly one per thread ----
    float local;
    {
        int r = t >> 6, x = t & 63;     // r = 0..7
        float s = 0.0f;
        #pragma unroll
        for (int d = -3; d <= 3; ++d)
            s += g[d + 3] * sm.s.tmp[r + 3 + d][x];
        out_smooth[b * CELLS + (y0 + r) * GRID + x] = s;
        float ov = s - 1.0f;
        ov = ov > 0.0f ? ov : 0.0f;
        local = ov * ov;
    }

    #pragma unroll
    for (int off = 32; off > 0; off >>= 1) local += __shfl_down(local, off, 64);
    if ((t & 63) == 0) sm.s.red[t >> 6] = local;
    __syncthreads();

    if (t == 0) {
        float share = 0.0f;
        #pragma unroll
        for (int i = 0; i < 8; ++i) share += sm.s.red[i];
        __hip_atomic_store(&sync->pen[b][q], share,
                           __ATOMIC_RELEASE, __HIP_MEMORY_SCOPE_AGENT);
        int r = __hip_atomic_fetch_add(&sync->cnt2[b], 1,
                                       __ATOMIC_ACQ_REL, __HIP_MEMORY_SCOPE_AGENT);
        if (r == NSLICE - 1) {
            float s = 0.0f;
            #pragma unroll
            for (int i = 0; i < NSLICE; ++i)
                s += __hip_atomic_load(&sync->pen[b][i],
                                       __ATOMIC_ACQUIRE, __HIP_MEMORY_SCOPE_AGENT);
            out_penalty[b] = s;
        }
    }
}

extern "C" void kernel_launch(void* const* d_in, const int* in_sizes, int n_in,
                              void* d_out, int out_size, void* d_ws, size_t ws_size,
                              hipStream_t stream) {
    const float* positions    = (const float*)d_in[0];
    const float* pin_offsets  = (const float*)d_in[1];
    const int*   net_to_pin   = (const int*)d_in[2];
    const int*   pin_to_macro = (const int*)d_in[3];
    float* out     = (float*)d_out;        // [0..3] penalty, [4..] rudy_smooth
    float* partial = (float*)d_ws;         // BATCH * NPART * 4096 f32 (~4 MB)
    SyncBlock* sync = (SyncBlock*)(partial + (size_t)BATCH * NPART * CELLS);

    hipMemsetAsync(sync, 0, sizeof(SyncBlock), stream);   // 160 B — cheap
    rudy_fused_kernel<<<dim3(NPART + NSLICE, BATCH), 512, 0, stream>>>(
        positions, pin_offsets, net_to_pin, pin_to_macro,
        partial, sync, out, out + BATCH);
}

// Round 6
// 71.700 us; speedup vs baseline: 1.9481x; 1.9481x over previous
//
#include <hip/hip_runtime.h>

#define GRID   64
#define CELLS  (GRID * GRID)
#define BATCH  4
#define NV     512
#define NNET   2000
#define MAXPIN 8
#define NB     32            // nets per stage-A block
#define NPART  63            // ceil(2000/32)
#define SROWS  14            // 8 output rows + 3 halo each side

// sigma(a)*sigma(b) = 1 / ((1+e^-a)(1+e^-b)) : 2 exp, 1 divide
__device__ __forceinline__ float sig2(float a, float b) {
    float e1 = __expf(-a);
    float e2 = __expf(-b);
    return 1.0f / ((1.0f + e1) * (1.0f + e2));
}

// Stage A: 252 blocks x 512 threads (full occupancy, 4 blocks/CU). Each block
// owns 32 nets, accumulates a private 64x64 partial in registers (8 cells/
// thread), stores it plain (no memset, no atomics). pb==0 zeroes out_penalty.
__global__ __launch_bounds__(512)
void rudy_partial_kernel(const float* __restrict__ positions,
                         const float* __restrict__ pin_offsets,
                         const int*   __restrict__ net_to_pin,
                         const int*   __restrict__ pin_to_macro,
                         float* __restrict__ partial,
                         float* __restrict__ out_penalty) {
    const int pb = blockIdx.x;      // partial index within batch (0..62)
    const int b  = blockIdx.y;
    const int t  = threadIdx.x;

    if (pb == 0 && t == 0) out_penalty[b] = 0.0f;

    __shared__ float s_inx[NB][GRID];   // in_x * inv_size (folded)
    __shared__ float s_iny[NB][GRID];
    __shared__ float s_xmin[NB], s_xmax[NB], s_ymin[NB], s_ymax[NB], s_inv[NB];

    const int n0 = pb * NB;

    // ---- A1: bbox per net, 8 lanes per net, threads 0..255 only ----
    if (t < 256) {
        const int nl = t >> 3;      // local net 0..31
        const int j  = t & 7;       // pin slot
        const int n  = n0 + nl;
        int pi = (n < NNET) ? net_to_pin[n * MAXPIN + j] : -1;
        int sp = pi > 0 ? pi : 0;
        int v  = pin_to_macro[sp];
        float px = positions[(b * NV + v) * 2 + 0] + pin_offsets[sp * 2 + 0];
        float py = positions[(b * NV + v) * 2 + 1] + pin_offsets[sp * 2 + 1];
        bool valid = pi >= 0;
        float xmx = valid ? px : -1e9f;
        float xmn = valid ? px :  1e9f;
        float ymx = valid ? py : -1e9f;
        float ymn = valid ? py :  1e9f;
        #pragma unroll
        for (int off = 1; off < 8; off <<= 1) {
            xmx = fmaxf(xmx, __shfl_xor(xmx, off, 64));
            xmn = fminf(xmn, __shfl_xor(xmn, off, 64));
            ymx = fmaxf(ymx, __shfl_xor(ymx, off, 64));
            ymn = fminf(ymn, __shfl_xor(ymn, off, 64));
        }
        if (j == 0) {
            float xming = (xmn + 1.0f) * 31.5f;   // (v+1)*0.5*(M-1)
            float xmaxg = (xmx + 1.0f) * 31.5f;
            float yming = (ymn + 1.0f) * 31.5f;
            float ymaxg = (ymx + 1.0f) * 31.5f;
            float size = fmaxf((xmaxg - xming + 1.0f) * (ymaxg - yming + 1.0f), 1.0f);
            s_xmin[nl] = xming; s_xmax[nl] = xmaxg;
            s_ymin[nl] = yming; s_ymax[nl] = ymaxg;
            s_inv[nl]  = 1.0f / size;
        }
    }
    __syncthreads();

    // ---- A2: fill in_x (scaled by inv) / in_y — 4096 vals, 8 per thread ----
    #pragma unroll
    for (int i = 0; i < 8; ++i) {
        int vv    = i * 512 + t;
        int n     = vv >> 7;          // net
        int rem   = vv & 127;
        int which = rem >> 6;         // 0 = x, 1 = y
        int coord = rem & 63;
        float c  = (float)coord;
        float lo = which ? s_ymin[n] : s_xmin[n];
        float hi = which ? s_ymax[n] : s_xmax[n];
        float val = sig2(2.0f * (c - lo + 0.5f), 2.0f * (hi - c + 0.5f));
        if (which) s_iny[n][coord] = val;
        else       s_inx[n][coord] = val * s_inv[n];
    }
    __syncthreads();

    // ---- C: rank-1 accumulate, 8 cells/thread over 32 nets ----
    const int lane = t & 63;        // x coordinate
    const int w    = t >> 6;        // wave id 0..7: rows y = w*8 .. w*8+7
    float acc[8];
    #pragma unroll
    for (int k = 0; k < 8; ++k) acc[k] = 0.0f;

    for (int n = 0; n < NB; ++n) {
        float xv = s_inx[n][lane];
        const float4* iny4 = (const float4*)&s_iny[n][w * 8];  // 32B aligned
        #pragma unroll
        for (int k4 = 0; k4 < 2; ++k4) {
            float4 yv = iny4[k4];
            acc[k4 * 4 + 0] += yv.x * xv;
            acc[k4 * 4 + 1] += yv.y * xv;
            acc[k4 * 4 + 2] += yv.z * xv;
            acc[k4 * 4 + 3] += yv.w * xv;
        }
    }

    // ---- plain coalesced store of this block's private partial ----
    float* dst = partial + ((size_t)b * NPART + pb) * CELLS;
    #pragma unroll
    for (int k = 0; k < 8; ++k)
        dst[(w * 8 + k) * GRID + lane] = acc[k];
}

// Stage B: grid (8, BATCH) x 512 threads. Block q owns output rows
// y0=q*8..q*8+7. 448 threads reduce the 14-row halo slice across the 63
// partials (2 threads per cell: 32/31 partials each, combined in LDS), then
// separable 7-tap Gaussian, 8 output rows, atomic penalty share.
__global__ __launch_bounds__(512)
void reduce_smooth_penalty_kernel(const float* __restrict__ partial,
                                  float* __restrict__ out_penalty,
                                  float* __restrict__ out_smooth) {
    const int q = blockIdx.x;       // row slice 0..7
    const int b = blockIdx.y;
    const int t = threadIdx.x;
    const int y0 = q * 8;

    __shared__ float tA  [SROWS][GRID];   // partial-sum half 0
    __shared__ float tB  [SROWS][GRID];   // partial-sum half 1
    __shared__ float tmp [SROWS][GRID];   // h-pass output
    __shared__ float red [8];

    // 1D gaussian, sigma=1.5, ksize=7, normalized (separable == normalized 2D)
    float g[7];
    {
        float s = 0.0f;
        #pragma unroll
        for (int i = 0; i < 7; ++i) {
            float d = (float)(i - 3);
            g[i] = expf(-d * d / 4.5f);
            s += g[i];
        }
        float inv = 1.0f / s;
        #pragma unroll
        for (int i = 0; i < 7; ++i) g[i] *= inv;
    }

    // ---- reduce slice across partials: 2 threads per (row, float4-col) ----
    if (t < 2 * SROWS * 16) {
        const int half = t >= SROWS * 16;        // 0 or 1
        const int i    = half ? t - SROWS * 16 : t;
        const int r    = i >> 4;                  // slice row 0..13
        const int c4   = i & 15;                  // float4 column
        const int yy   = y0 - 3 + r;              // global row
        const int p0   = half ? 32 : 0;
        const int p1   = half ? NPART : 32;
        float4 a0 = {0,0,0,0}, a1 = {0,0,0,0};
        if (yy >= 0 && yy < GRID) {
            const float4* src = (const float4*)(partial + (size_t)b * NPART * CELLS)
                                + (size_t)yy * 16 + c4;
            int p = p0;
            for (; p + 1 < p1; p += 2) {          // 2 independent chains
                float4 v0 = src[(size_t)(p + 0) * (CELLS / 4)];
                float4 v1 = src[(size_t)(p + 1) * (CELLS / 4)];
                a0.x += v0.x; a0.y += v0.y; a0.z += v0.z; a0.w += v0.w;
                a1.x += v1.x; a1.y += v1.y; a1.z += v1.z; a1.w += v1.w;
            }
            for (; p < p1; ++p) {
                float4 v0 = src[(size_t)p * (CELLS / 4)];
                a0.x += v0.x; a0.y += v0.y; a0.z += v0.z; a0.w += v0.w;
            }
            a0.x += a1.x; a0.y += a1.y; a0.z += a1.z; a0.w += a1.w;
        }
        if (half) ((float4*)&tB[r][0])[c4] = a0;  // zeros for out-of-range rows
        else      ((float4*)&tA[r][0])[c4] = a0;
    }
    __syncthreads();

    // ---- horizontal pass (zero x-padding): 896 cells over 512 threads ----
    for (int i = t; i < SROWS * GRID; i += 512) {
        int r = i >> 6, x = i & 63;
        float s = 0.0f;
        #pragma unroll
        for (int d = -3; d <= 3; ++d) {
            int xx = x + d;
            if (xx >= 0 && xx < GRID)
                s += g[d + 3] * (tA[r][xx] + tB[r][xx]);
        }
        tmp[r][x] = s;
    }
    __syncthreads();

    // ---- vertical pass: 512 cells, exactly one per thread ----
    float local;
    {
        int r = t >> 6, x = t & 63;     // r = 0..7
        float s = 0.0f;
        #pragma unroll
        for (int d = -3; d <= 3; ++d)
            s += g[d + 3] * tmp[r + 3 + d][x];   // halo rows already zeroed
        out_smooth[b * CELLS + (y0 + r) * GRID + x] = s;
        float ov = s - 1.0f;
        ov = ov > 0.0f ? ov : 0.0f;
        local = ov * ov;
    }

    #pragma unroll
    for (int off = 32; off > 0; off >>= 1) local += __shfl_down(local, off, 64);
    if ((t & 63) == 0) red[t >> 6] = local;
    __syncthreads();
    if (t == 0) {
        float share = 0.0f;
        #pragma unroll
        for (int i = 0; i < 8; ++i) share += red[i];
        atomicAdd(&out_penalty[b], share);
    }
}

extern "C" void kernel_launch(void* const* d_in, const int* in_sizes, int n_in,
                              void* d_out, int out_size, void* d_ws, size_t ws_size,
                              hipStream_t stream) {
    const float* positions    = (const float*)d_in[0];
    const float* pin_offsets  = (const float*)d_in[1];
    const int*   net_to_pin   = (const int*)d_in[2];
    const int*   pin_to_macro = (const int*)d_in[3];
    float* out     = (float*)d_out;        // [0..3] penalty, [4..] rudy_smooth
    float* partial = (float*)d_ws;         // BATCH * NPART * 4096 f32 (~4 MB)

    rudy_partial_kernel<<<dim3(NPART, BATCH), 512, 0, stream>>>(
        positions, pin_offsets, net_to_pin, pin_to_macro, partial, out);
    reduce_smooth_penalty_kernel<<<dim3(8, BATCH), 512, 0, stream>>>(
        partial, out, out + BATCH);
}

// Round 7
// 69.863 us; speedup vs baseline: 1.9993x; 1.0263x over previous
//
#include <hip/hip_runtime.h>

#define GRID   64
#define CELLS  (GRID * GRID)
#define BATCH  4
#define NV     512
#define NNET   2000
#define MAXPIN 8
#define NB     32            // nets per stage-A block
#define NPART  63            // ceil(2000/32)
#define SROWS  14            // 8 output rows + 3 halo each side

// sigma(a)*sigma(b) = 1 / ((1+e^-a)(1+e^-b)) : 2 exp, 1 divide
__device__ __forceinline__ float sig2(float a, float b) {
    float e1 = __expf(-a);
    float e2 = __expf(-b);
    return 1.0f / ((1.0f + e1) * (1.0f + e2));
}

// Stage A: 252 blocks x 512 threads. Each block owns 32 nets, accumulates a
// private 64x64 partial in registers (8 cells/thread), stores it plain
// (no memset, no atomics). pb==0 zeroes out_penalty[b].
__global__ __launch_bounds__(512)
void rudy_partial_kernel(const float* __restrict__ positions,
                         const float* __restrict__ pin_offsets,
                         const int*   __restrict__ net_to_pin,
                         const int*   __restrict__ pin_to_macro,
                         float* __restrict__ partial,
                         float* __restrict__ out_penalty) {
    const int pb = blockIdx.x;      // partial index within batch (0..62)
    const int b  = blockIdx.y;
    const int t  = threadIdx.x;

    if (pb == 0 && t == 0) out_penalty[b] = 0.0f;

    __shared__ float s_inx[NB][GRID];   // in_x * inv_size (folded)
    __shared__ float s_iny[NB][GRID];
    __shared__ float s_xmin[NB], s_xmax[NB], s_ymin[NB], s_ymax[NB], s_inv[NB];

    const int n0 = pb * NB;

    // ---- A1: bbox per net, 8 lanes per net, threads 0..255 only ----
    if (t < 256) {
        const int nl = t >> 3;      // local net 0..31
        const int j  = t & 7;       // pin slot
        const int n  = n0 + nl;
        int pi = (n < NNET) ? net_to_pin[n * MAXPIN + j] : -1;
        int sp = pi > 0 ? pi : 0;
        int v  = pin_to_macro[sp];
        float px = positions[(b * NV + v) * 2 + 0] + pin_offsets[sp * 2 + 0];
        float py = positions[(b * NV + v) * 2 + 1] + pin_offsets[sp * 2 + 1];
        bool valid = pi >= 0;
        float xmx = valid ? px : -1e9f;
        float xmn = valid ? px :  1e9f;
        float ymx = valid ? py : -1e9f;
        float ymn = valid ? py :  1e9f;
        #pragma unroll
        for (int off = 1; off < 8; off <<= 1) {
            xmx = fmaxf(xmx, __shfl_xor(xmx, off, 64));
            xmn = fminf(xmn, __shfl_xor(xmn, off, 64));
            ymx = fmaxf(ymx, __shfl_xor(ymx, off, 64));
            ymn = fminf(ymn, __shfl_xor(ymn, off, 64));
        }
        if (j == 0) {
            float xming = (xmn + 1.0f) * 31.5f;   // (v+1)*0.5*(M-1)
            float xmaxg = (xmx + 1.0f) * 31.5f;
            float yming = (ymn + 1.0f) * 31.5f;
            float ymaxg = (ymx + 1.0f) * 31.5f;
            float size = fmaxf((xmaxg - xming + 1.0f) * (ymaxg - yming + 1.0f), 1.0f);
            s_xmin[nl] = xming; s_xmax[nl] = xmaxg;
            s_ymin[nl] = yming; s_ymax[nl] = ymaxg;
            s_inv[nl]  = 1.0f / size;
        }
    }
    __syncthreads();

    // ---- A2: fill in_x (scaled by inv) / in_y — 4096 vals, 8 per thread ----
    #pragma unroll
    for (int i = 0; i < 8; ++i) {
        int vv    = i * 512 + t;
        int n     = vv >> 7;          // net
        int rem   = vv & 127;
        int which = rem >> 6;         // 0 = x, 1 = y
        int coord = rem & 63;
        float c  = (float)coord;
        float lo = which ? s_ymin[n] : s_xmin[n];
        float hi = which ? s_ymax[n] : s_xmax[n];
        float val = sig2(2.0f * (c - lo + 0.5f), 2.0f * (hi - c + 0.5f));
        if (which) s_iny[n][coord] = val;
        else       s_inx[n][coord] = val * s_inv[n];
    }
    __syncthreads();

    // ---- C: rank-1 accumulate, 8 cells/thread over 32 nets ----
    const int lane = t & 63;        // x coordinate
    const int w    = t >> 6;        // wave id 0..7: rows y = w*8 .. w*8+7
    float acc[8];
    #pragma unroll
    for (int k = 0; k < 8; ++k) acc[k] = 0.0f;

    for (int n = 0; n < NB; ++n) {
        float xv = s_inx[n][lane];
        const float4* iny4 = (const float4*)&s_iny[n][w * 8];  // 32B aligned
        #pragma unroll
        for (int k4 = 0; k4 < 2; ++k4) {
            float4 yv = iny4[k4];
            acc[k4 * 4 + 0] += yv.x * xv;
            acc[k4 * 4 + 1] += yv.y * xv;
            acc[k4 * 4 + 2] += yv.z * xv;
            acc[k4 * 4 + 3] += yv.w * xv;
        }
    }

    // ---- plain coalesced store of this block's private partial ----
    float* dst = partial + ((size_t)b * NPART + pb) * CELLS;
    #pragma unroll
    for (int k = 0; k < 8; ++k)
        dst[(w * 8 + k) * GRID + lane] = acc[k];
}

// Stage B: grid (8, BATCH) x 512 threads. Block q owns output rows
// y0=q*8..q*8+7. 448 threads reduce the 14-row halo slice across the 63
// partials (2 threads per cell, 4 independent accumulator chains each for
// memory-level parallelism), then separable 7-tap Gaussian, 8 output rows,
// atomic penalty share.
__global__ __launch_bounds__(512)
void reduce_smooth_penalty_kernel(const float* __restrict__ partial,
                                  float* __restrict__ out_penalty,
                                  float* __restrict__ out_smooth) {
    const int q = blockIdx.x;       // row slice 0..7
    const int b = blockIdx.y;
    const int t = threadIdx.x;
    const int y0 = q * 8;

    __shared__ float tA  [SROWS][GRID];   // partial-sum half 0
    __shared__ float tB  [SROWS][GRID];   // partial-sum half 1
    __shared__ float tmp [SROWS][GRID];   // h-pass output
    __shared__ float red [8];

    // 1D gaussian, sigma=1.5, ksize=7, normalized (separable == normalized 2D)
    float g[7];
    {
        float s = 0.0f;
        #pragma unroll
        for (int i = 0; i < 7; ++i) {
            float d = (float)(i - 3);
            g[i] = expf(-d * d / 4.5f);
            s += g[i];
        }
        float inv = 1.0f / s;
        #pragma unroll
        for (int i = 0; i < 7; ++i) g[i] *= inv;
    }

    // ---- reduce slice across partials: 2 threads per (row, float4-col),
    //      4 independent chains per thread (depth ~8 L3-latency waits) ----
    if (t < 2 * SROWS * 16) {
        const int half = t >= SROWS * 16;        // 0 or 1
        const int i    = half ? t - SROWS * 16 : t;
        const int r    = i >> 4;                  // slice row 0..13
        const int c4   = i & 15;                  // float4 column
        const int yy   = y0 - 3 + r;              // global row
        const int p0   = half ? 32 : 0;
        const int p1   = half ? NPART : 32;
        float4 a0 = {0,0,0,0}, a1 = {0,0,0,0}, a2 = {0,0,0,0}, a3 = {0,0,0,0};
        if (yy >= 0 && yy < GRID) {
            const float4* src = (const float4*)(partial + (size_t)b * NPART * CELLS)
                                + (size_t)yy * 16 + c4;
            int p = p0;
            for (; p + 3 < p1; p += 4) {          // 4 independent chains
                float4 v0 = src[(size_t)(p + 0) * (CELLS / 4)];
                float4 v1 = src[(size_t)(p + 1) * (CELLS / 4)];
                float4 v2 = src[(size_t)(p + 2) * (CELLS / 4)];
                float4 v3 = src[(size_t)(p + 3) * (CELLS / 4)];
                a0.x += v0.x; a0.y += v0.y; a0.z += v0.z; a0.w += v0.w;
                a1.x += v1.x; a1.y += v1.y; a1.z += v1.z; a1.w += v1.w;
                a2.x += v2.x; a2.y += v2.y; a2.z += v2.z; a2.w += v2.w;
                a3.x += v3.x; a3.y += v3.y; a3.z += v3.z; a3.w += v3.w;
            }
            for (; p < p1; ++p) {
                float4 v0 = src[(size_t)p * (CELLS / 4)];
                a0.x += v0.x; a0.y += v0.y; a0.z += v0.z; a0.w += v0.w;
            }
            a0.x += a1.x + a2.x + a3.x;
            a0.y += a1.y + a2.y + a3.y;
            a0.z += a1.z + a2.z + a3.z;
            a0.w += a1.w + a2.w + a3.w;
        }
        if (half) ((float4*)&tB[r][0])[c4] = a0;  // zeros for out-of-range rows
        else      ((float4*)&tA[r][0])[c4] = a0;
    }
    __syncthreads();

    // ---- horizontal pass (zero x-padding): 896 cells over 512 threads ----
    for (int i = t; i < SROWS * GRID; i += 512) {
        int r = i >> 6, x = i & 63;
        float s = 0.0f;
        #pragma unroll
        for (int d = -3; d <= 3; ++d) {
            int xx = x + d;
            if (xx >= 0 && xx < GRID)
                s += g[d + 3] * (tA[r][xx] + tB[r][xx]);
        }
        tmp[r][x] = s;
    }
    __syncthreads();

    // ---- vertical pass: 512 cells, exactly one per thread ----
    float local;
    {
        int r = t >> 6, x = t & 63;     // r = 0..7
        float s = 0.0f;
        #pragma unroll
        for (int d = -3; d <= 3; ++d)
            s += g[d + 3] * tmp[r + 3 + d][x];   // halo rows already zeroed
        out_smooth[b * CELLS + (y0 + r) * GRID + x] = s;
        float ov = s - 1.0f;
        ov = ov > 0.0f ? ov : 0.0f;
        local = ov * ov;
    }

    #pragma unroll
    for (int off = 32; off > 0; off >>= 1) local += __shfl_down(local, off, 64);
    if ((t & 63) == 0) red[t >> 6] = local;
    __syncthreads();
    if (t == 0) {
        float share = 0.0f;
        #pragma unroll
        for (int i = 0; i < 8; ++i) share += red[i];
        atomicAdd(&out_penalty[b], share);
    }
}

extern "C" void kernel_launch(void* const* d_in, const int* in_sizes, int n_in,
                              void* d_out, int out_size, void* d_ws, size_t ws_size,
                              hipStream_t stream) {
    const float* positions    = (const float*)d_in[0];
    const float* pin_offsets  = (const float*)d_in[1];
    const int*   net_to_pin   = (const int*)d_in[2];
    const int*   pin_to_macro = (const int*)d_in[3];
    float* out     = (float*)d_out;        // [0..3] penalty, [4..] rudy_smooth
    float* partial = (float*)d_ws;         // BATCH * NPART * 4096 f32 (~4 MB)

    rudy_partial_kernel<<<dim3(NPART, BATCH), 512, 0, stream>>>(
        positions, pin_offsets, net_to_pin, pin_to_macro, partial, out);
    reduce_smooth_penalty_kernel<<<dim3(8, BATCH), 512, 0, stream>>>(
        partial, out, out + BATCH);
}